// Round 1
// baseline (467.604 us; speedup 1.0000x reference)
//
#include <hip/hip_runtime.h>
#include <hip/hip_bf16.h>
#include <stdint.h>

#define S_LEN   4096
#define DIN     1280
#define DOUT    1280
#define N_LORA  4
#define R_LORA  16
#define M_TOT   32768               // B*S = 8*4096
#define KC      (DIN + N_LORA*R_LORA)   // 1344
#define NR      64                  // N_LORA*R_LORA
#define NT      21                  // K tiles of 64: 20 from xb + 1 from g

typedef __attribute__((ext_vector_type(4))) float floatx4;
typedef __attribute__((ext_vector_type(8))) short shortx8;

typedef union { uint4 u; shortx8 s; } punx8;

static __device__ __forceinline__ unsigned short bf16_rne(float f) {
    union { float f; unsigned u; } v; v.f = f;
    unsigned u = v.u;
    u += 0x7fffu + ((u >> 16) & 1u);   // round-to-nearest-even
    return (unsigned short)(u >> 16);
}

static __device__ __forceinline__ void async16(const unsigned short* g, unsigned short* l) {
    __builtin_amdgcn_global_load_lds(
        (const __attribute__((address_space(1))) unsigned int*)g,
        (__attribute__((address_space(3))) unsigned int*)l, 16, 0, 0);
}

static __device__ __forceinline__ uint4 cvt8(const float* src) {
    const float4* p = (const float4*)src;
    float4 a = p[0], b = p[1];
    uint4 o;
    o.x = (unsigned)bf16_rne(a.x) | ((unsigned)bf16_rne(a.y) << 16);
    o.y = (unsigned)bf16_rne(a.z) | ((unsigned)bf16_rne(a.w) << 16);
    o.z = (unsigned)bf16_rne(b.x) | ((unsigned)bf16_rne(b.y) << 16);
    o.w = (unsigned)bf16_rne(b.z) | ((unsigned)bf16_rne(b.w) << 16);
    return o;
}

// counted vmcnt wait + raw barrier (no implicit vmcnt(0) drain — this is the T4 lever)
#define VMCNT(n) asm volatile("s_waitcnt vmcnt(" #n ")" ::: "memory")
static __device__ __forceinline__ void barx() {
    asm volatile("" ::: "memory");
    __builtin_amdgcn_s_barrier();
    asm volatile("" ::: "memory");
}

// ---- Kernel 1: x (fp32) -> xb (bf16, dense 32768 x 1280). Pure streaming.
__global__ __launch_bounds__(256) void k_convert_x(const float* __restrict__ x,
                                                   unsigned short* __restrict__ xb) {
    size_t e = ((size_t)blockIdx.x * 256 + threadIdx.x) * 8;
    *(uint4*)(xb + e) = cvt8(x + e);
}

// ---- Kernel 2: Wcat[o, 0:1280] = W[o,:];  Wcat[o, 1280 + n*16 + r] = Bw[n,o,r]
__global__ __launch_bounds__(256) void k_build_wcat(const float* __restrict__ W,
                                                    const float* __restrict__ Bw,
                                                    unsigned short* __restrict__ Wcat) {
    int i = blockIdx.x * 256 + threadIdx.x;   // 215,040 threads
    int e = i * 8;
    int o = e / KC;
    int c = e - o * KC;                       // multiple of 8
    const float* src;
    if (c < DIN) {
        src = W + o * DIN + c;
    } else {
        int j = c - DIN;                      // 0..63, multiple of 8
        int n = j >> 4, r = j & 15;           // r in {0,8}
        src = Bw + (n * DOUT + o) * R_LORA + r;
    }
    *(uint4*)(Wcat + o * KC + c) = cvt8(src);
}

// ---- Kernel 3: A (4,16,1280) fp32 -> Abp fragment-major bf16
__global__ __launch_bounds__(256) void k_convert_abp(const float* __restrict__ A,
                                                     unsigned short* __restrict__ Abp) {
    int step = blockIdx.x;                    // 40 blocks
    int t = threadIdx.x;
    int ct = t >> 6, lane = t & 63;
    int mi = lane & 15, kq = lane >> 4;
    const float* src = A + (ct * 16 + mi) * DIN + step * 32 + kq * 8;
    *(uint4*)(Abp + ((size_t)(step * 4 + ct) * 64 + lane) * 8) = cvt8(src);
}

// ---- Kernel 4: g[m, n*16+r] = scal[n]*mask[n,s(m)] * (xb @ A^T)
__global__ __launch_bounds__(1024) void k_lora_g(const unsigned short* __restrict__ xb,
                                                 const unsigned short* __restrict__ Abp,
                                                 const float* __restrict__ scalings,
                                                 const float* __restrict__ masks,
                                                 unsigned short* __restrict__ g) {
    __shared__ float hs[4][64][64];           // [kg][row][rank] fp32 partials
    int tid = threadIdx.x;
    int wave = tid >> 6, lane = tid & 63;
    int kg = wave >> 2, wv = wave & 3;
    int mi = lane & 15, kq = lane >> 4;
    int m0 = blockIdx.x * 64;                 // 512 blocks

    const unsigned short* xrow = xb + (size_t)(m0 + wv * 16 + mi) * DIN;

    floatx4 acc[4] = {};
    for (int s = 0; s < 10; ++s) {
        int step = kg * 10 + s;               // global 32-wide k-step, 0..39
        int k = step * 32 + kq * 8;
        shortx8 xf = *(const shortx8*)(xrow + k);
#pragma unroll
        for (int ct = 0; ct < 4; ++ct) {
            shortx8 bfr = *(const shortx8*)(Abp + ((size_t)(step * 4 + ct) * 64 + lane) * 8);
            acc[ct] = __builtin_amdgcn_mfma_f32_16x16x32_bf16(xf, bfr, acc[ct], 0, 0, 0);
        }
    }
#pragma unroll
    for (int ct = 0; ct < 4; ++ct)
#pragma unroll
        for (int reg = 0; reg < 4; ++reg)
            hs[kg][wv * 16 + kq * 4 + reg][ct * 16 + mi] = acc[ct][reg];
    __syncthreads();

    int r = tid >> 4;                         // 0..63 local row
    int c0 = (tid & 15) * 4;                  // 0..60 rank col (4-aligned)
    float4 s0 = *(const float4*)&hs[0][r][c0];
    float4 s1 = *(const float4*)&hs[1][r][c0];
    float4 s2 = *(const float4*)&hs[2][r][c0];
    float4 s3 = *(const float4*)&hs[3][r][c0];
    int n = c0 >> 4;                          // adapter (c0..c0+3 share it)
    int m = m0 + r;
    float wgt = scalings[n] * masks[n * S_LEN + (m & (S_LEN - 1))];
    float v0 = (s0.x + s1.x + s2.x + s3.x) * wgt;
    float v1 = (s0.y + s1.y + s2.y + s3.y) * wgt;
    float v2 = (s0.z + s1.z + s2.z + s3.z) * wgt;
    float v3 = (s0.w + s1.w + s2.w + s3.w) * wgt;
    uint2 packed;
    packed.x = (unsigned)bf16_rne(v0) | ((unsigned)bf16_rne(v1) << 16);
    packed.y = (unsigned)bf16_rne(v2) | ((unsigned)bf16_rne(v3) << 16);
    *(uint2*)(g + (size_t)m * NR + c0) = packed;
}

// ---- Kernel 5: out = [xb | g] @ Wcat^T + bias  (M=32768, N=1280, K=1344)
// Pipelined rewrite (T2+T3+T4+T5):
//   BM=256, BN=128, BK=64; 512 threads = 8 waves (4M x 2N), wave tile 64x64.
//   LDS 96 KiB: As[2][256][64] + Bs[2][128][64] bf16, rows = 128 B,
//   XOR-swizzled (byte ^= (row&7)<<4) -> ds_read_b128 2-way (free) instead of 8-way.
//   global_load_lds writes LINEARLY; source address carries the inverse swizzle
//   (rule #21: both-sides-or-neither).
//   2 phases per K-tile; counted vmcnt(4) once per tile (never 0 in steady state);
//   raw s_barrier (no implicit drain). Stage schedule (correct by construction):
//     q0: read ALL A frags + B frags nf0,nf1; stage B(t+1) -> other buffer
//     q1: read B frags nf2,nf3;              stage A(t+2) -> current buffer
//   (A region of current buffer is fully consumed in q0; q0-end barrier frees it.)
__global__ __launch_bounds__(512, 2) void k_main_gemm(const unsigned short* __restrict__ xb,
                                                      const unsigned short* __restrict__ g,
                                                      const unsigned short* __restrict__ Wcat,
                                                      const float* __restrict__ bias,
                                                      float* __restrict__ out) {
    __shared__ alignas(16) unsigned short As[2][256 * 64];
    __shared__ alignas(16) unsigned short Bs[2][128 * 64];

    const int tid = threadIdx.x;
    const int wave = tid >> 6, lane = tid & 63;
    const int wm = wave >> 1, wn = wave & 1;        // 4M x 2N wave grid
    const int mi = lane & 15, kq = lane >> 4;

    // XCD-bijective swizzle: 1280 blocks = 8 XCDs x 160 slots; per XCD 16 row-tiles x 10 col-tiles,
    // col fastest -> a row-tile's xb panel (688 KB) stays L2-hot across its 10 col-tiles.
    int bx = blockIdx.x;
    int xcd = bx & 7, slot = bx >> 3;
    int srb = slot / 10;
    const int m0 = (xcd * 16 + srb) * 256;
    const int n0 = (slot - srb * 10) * 128;

    // staging: chunk = 64 rows x 64 cols = 8 KB = 1 load/thread.
    // thread covers linear LDS 16B-slot idx = c*512+tid; row = idx>>3; slot-in-row = idx&7.
    // inverse swizzle on the GLOBAL column so that swizzled-read finds it:
    const int tr = tid >> 3;                        // row within chunk
    const int ts = (tid & 7) ^ (tr & 7);            // pre-swizzled 16B column slot

    // read-side swizzle constants (row&7 == mi&7 for every fragment row)
    const int sw  = (mi & 7) << 4;
    const int cA  = (wm * 64 + mi) * 128;           // A fragment row base (bytes)
    const int cB  = (wn * 64 + mi) * 128;           // B fragment row base (bytes)
    const int co0 = (kq * 16) ^ sw;                 // k-sub 0 column (bytes)
    const int co1 = (64 + kq * 16) ^ sw;            // k-sub 1 column (bytes)

    floatx4 acc[4][4] = {};

    auto stageA = [&](int t, int b) {               // all 4 A chunks (256 rows) of K-tile t
#pragma unroll
        for (int c = 0; c < 4; ++c) {
            int r = c * 64 + tr;
            const unsigned short* src = (t < 20)
                ? xb + (size_t)(m0 + r) * DIN + t * 64 + ts * 8
                : g  + (size_t)(m0 + r) * NR  + ts * 8;        // tile 20 = LoRA columns
            async16(src, &As[b][(c * 512 + tid) * 8]);
        }
    };
    auto stageB = [&](int t, int b) {               // both B chunks (128 rows)
#pragma unroll
        for (int c = 0; c < 2; ++c) {
            int r = c * 64 + tr;
            async16(Wcat + (size_t)(n0 + r) * KC + t * 64 + ts * 8,
                    &Bs[b][(c * 512 + tid) * 8]);
        }
    };

    // prologue: A(0),B(0) -> buf0; A(1) -> buf1.  10 loads; wait until tile 0 landed
    // (4 outstanding = A(1)), then barrier.
    stageA(0, 0);
    stageB(0, 0);
    stageA(1, 1);
    VMCNT(4);
    barx();

    for (int t = 0; t < NT; ++t) {
        const int cur = t & 1;
        const char* Ab = (const char*)As[cur];
        const char* Bb = (const char*)Bs[cur];

        shortx8 a[4][2], bfr[4][2];

        // ===== phase q0: all A frags + low B frags; stage B(t+1); MFMA m x n{0,1}
#pragma unroll
        for (int f = 0; f < 4; ++f) {
            const char* p = Ab + cA + f * (16 * 128);
            a[f][0] = *(const shortx8*)(p + co0);
            a[f][1] = *(const shortx8*)(p + co1);
        }
#pragma unroll
        for (int nf = 0; nf < 2; ++nf) {
            const char* p = Bb + cB + nf * (16 * 128);
            bfr[nf][0] = *(const shortx8*)(p + co0);
            bfr[nf][1] = *(const shortx8*)(p + co1);
        }
        if (t + 1 < NT) stageB(t + 1, cur ^ 1);
        barx();
        __builtin_amdgcn_s_setprio(1);
#pragma unroll
        for (int f = 0; f < 4; ++f)
#pragma unroll
            for (int nf = 0; nf < 2; ++nf) {
                acc[f][nf] = __builtin_amdgcn_mfma_f32_16x16x32_bf16(a[f][0], bfr[nf][0], acc[f][nf], 0, 0, 0);
                acc[f][nf] = __builtin_amdgcn_mfma_f32_16x16x32_bf16(a[f][1], bfr[nf][1], acc[f][nf], 0, 0, 0);
            }
        __builtin_amdgcn_s_setprio(0);
        barx();   // frees this buffer's A region for q1's stageA

        // ===== phase q1: high B frags; stage A(t+2) into freed A region; MFMA m x n{2,3}
#pragma unroll
        for (int nf = 2; nf < 4; ++nf) {
            const char* p = Bb + cB + nf * (16 * 128);
            bfr[nf][0] = *(const shortx8*)(p + co0);
            bfr[nf][1] = *(const shortx8*)(p + co1);
        }
        if (t + 2 < NT) stageA(t + 2, cur);
        barx();
        __builtin_amdgcn_s_setprio(1);
#pragma unroll
        for (int f = 0; f < 4; ++f)
#pragma unroll
            for (int nf = 2; nf < 4; ++nf) {
                acc[f][nf] = __builtin_amdgcn_mfma_f32_16x16x32_bf16(a[f][0], bfr[nf][0], acc[f][nf], 0, 0, 0);
                acc[f][nf] = __builtin_amdgcn_mfma_f32_16x16x32_bf16(a[f][1], bfr[nf][1], acc[f][nf], 0, 0, 0);
            }
        __builtin_amdgcn_s_setprio(0);
        // derived waits: steady state leaves A(t+3) (4 loads) in flight; tail drains.
        if (t < 19)      { VMCNT(4); }
        else if (t == 19){ VMCNT(0); }
        barx();
    }

    // epilogue: C/D layout col=lane&15, row=(lane>>4)*4+reg
#pragma unroll
    for (int nf = 0; nf < 4; ++nf) {
        int col = n0 + wn * 64 + nf * 16 + mi;
        float bv = bias[col];
#pragma unroll
        for (int f = 0; f < 4; ++f) {
            int row = m0 + wm * 64 + f * 16 + kq * 4;
            float* op = out + (size_t)row * DOUT + col;
#pragma unroll
            for (int reg = 0; reg < 4; ++reg)
                op[(size_t)reg * DOUT] = acc[f][nf][reg] + bv;
        }
    }
}

extern "C" void kernel_launch(void* const* d_in, const int* in_sizes, int n_in,
                              void* d_out, int out_size, void* d_ws, size_t ws_size,
                              hipStream_t stream) {
    const float* x     = (const float*)d_in[0];  // (8,4096,1280)
    const float* W     = (const float*)d_in[1];  // (1280,1280)
    const float* bias  = (const float*)d_in[2];  // (1280,)
    const float* A     = (const float*)d_in[3];  // (4,16,1280)
    const float* Bw    = (const float*)d_in[4];  // (4,1280,16)
    const float* scal  = (const float*)d_in[5];  // (4,)
    const float* masks = (const float*)d_in[6];  // (4,4096)
    float* out = (float*)d_out;

    unsigned short* xb   = (unsigned short*)d_ws;            // 32768 x 1280 bf16
    unsigned short* g    = xb + (size_t)M_TOT * DIN;         // 32768 x 64 bf16
    unsigned short* Wcat = g + (size_t)M_TOT * NR;           // 1280 x 1344 bf16
    unsigned short* Abp  = Wcat + (size_t)DOUT * KC;         // 40*4*64*8 bf16

    k_convert_x<<<(M_TOT * DIN) / (8 * 256), 256, 0, stream>>>(x, xb);
    k_build_wcat<<<(DOUT * KC) / (8 * 256), 256, 0, stream>>>(W, Bw, Wcat);
    k_convert_abp<<<DIN / 32, 256, 0, stream>>>(A, Abp);
    k_lora_g<<<M_TOT / 64, 1024, 0, stream>>>(xb, Abp, scal, masks, g);
    k_main_gemm<<<(M_TOT / 256) * (DOUT / 128), 512, 0, stream>>>(xb, g, Wcat, bias, out);
}

// Round 3
// 434.762 us; speedup vs baseline: 1.0755x; 1.0755x over previous
//
#include <hip/hip_runtime.h>
#include <hip/hip_bf16.h>
#include <stdint.h>

#define S_LEN   4096
#define DIN     1280
#define DOUT    1280
#define N_LORA  4
#define R_LORA  16
#define M_TOT   32768               // B*S = 8*4096
#define KC      (DIN + N_LORA*R_LORA)   // 1344
#define NR      64                  // N_LORA*R_LORA

typedef __attribute__((ext_vector_type(4))) float floatx4;
typedef __attribute__((ext_vector_type(8))) short shortx8;

static __device__ __forceinline__ unsigned short bf16_rne(float f) {
    union { float f; unsigned u; } v; v.f = f;
    unsigned u = v.u;
    u += 0x7fffu + ((u >> 16) & 1u);   // round-to-nearest-even
    return (unsigned short)(u >> 16);
}

static __device__ __forceinline__ void async16(const unsigned short* g, unsigned short* l) {
    __builtin_amdgcn_global_load_lds(
        (const __attribute__((address_space(1))) unsigned int*)g,
        (__attribute__((address_space(3))) unsigned int*)l, 16, 0, 0);
}

static __device__ __forceinline__ uint4 cvt8(const float* src) {
    const float4* p = (const float4*)src;
    float4 a = p[0], b = p[1];
    uint4 o;
    o.x = (unsigned)bf16_rne(a.x) | ((unsigned)bf16_rne(a.y) << 16);
    o.y = (unsigned)bf16_rne(a.z) | ((unsigned)bf16_rne(a.w) << 16);
    o.z = (unsigned)bf16_rne(b.x) | ((unsigned)bf16_rne(b.y) << 16);
    o.w = (unsigned)bf16_rne(b.z) | ((unsigned)bf16_rne(b.w) << 16);
    return o;
}

// counted vmcnt wait; raw barrier (no implicit vmcnt drain); lgkm drain + sched pin
#define VMCNT(n) asm volatile("s_waitcnt vmcnt(" #n ")" ::: "memory")
#define LGKM0    do { asm volatile("s_waitcnt lgkmcnt(0)" ::: "memory"); \
                      __builtin_amdgcn_sched_barrier(0); } while (0)
static __device__ __forceinline__ void barx() {
    asm volatile("" ::: "memory");
    __builtin_amdgcn_s_barrier();
    asm volatile("" ::: "memory");
}

// ---- Kernel 1: x (fp32) -> xb (bf16, dense 32768 x 1280). Pure streaming.
__global__ __launch_bounds__(256) void k_convert_x(const float* __restrict__ x,
                                                   unsigned short* __restrict__ xb) {
    size_t e = ((size_t)blockIdx.x * 256 + threadIdx.x) * 8;
    *(uint4*)(xb + e) = cvt8(x + e);
}

// ---- Kernel 2: Wcat[o, 0:1280] = W[o,:];  Wcat[o, 1280 + n*16 + r] = Bw[n,o,r]
__global__ __launch_bounds__(256) void k_build_wcat(const float* __restrict__ W,
                                                    const float* __restrict__ Bw,
                                                    unsigned short* __restrict__ Wcat) {
    int i = blockIdx.x * 256 + threadIdx.x;   // 215,040 threads
    int e = i * 8;
    int o = e / KC;
    int c = e - o * KC;                       // multiple of 8
    const float* src;
    if (c < DIN) {
        src = W + o * DIN + c;
    } else {
        int j = c - DIN;                      // 0..63, multiple of 8
        int n = j >> 4, r = j & 15;           // r in {0,8}
        src = Bw + (n * DOUT + o) * R_LORA + r;
    }
    *(uint4*)(Wcat + o * KC + c) = cvt8(src);
}

// ---- Kernel 3: A (4,16,1280) fp32 -> Abp fragment-major bf16
__global__ __launch_bounds__(256) void k_convert_abp(const float* __restrict__ A,
                                                     unsigned short* __restrict__ Abp) {
    int step = blockIdx.x;                    // 40 blocks
    int t = threadIdx.x;
    int ct = t >> 6, lane = t & 63;
    int mi = lane & 15, kq = lane >> 4;
    const float* src = A + (ct * 16 + mi) * DIN + step * 32 + kq * 8;
    *(uint4*)(Abp + ((size_t)(step * 4 + ct) * 64 + lane) * 8) = cvt8(src);
}

// ---- Kernel 4: g[m, n*16+r] = scal[n]*mask[n,s(m)] * (xb @ A^T)
__global__ __launch_bounds__(1024) void k_lora_g(const unsigned short* __restrict__ xb,
                                                 const unsigned short* __restrict__ Abp,
                                                 const float* __restrict__ scalings,
                                                 const float* __restrict__ masks,
                                                 unsigned short* __restrict__ g) {
    __shared__ float hs[4][64][64];           // [kg][row][rank] fp32 partials
    int tid = threadIdx.x;
    int wave = tid >> 6, lane = tid & 63;
    int kg = wave >> 2, wv = wave & 3;
    int mi = lane & 15, kq = lane >> 4;
    int m0 = blockIdx.x * 64;                 // 512 blocks

    const unsigned short* xrow = xb + (size_t)(m0 + wv * 16 + mi) * DIN;

    floatx4 acc[4] = {};
    for (int s = 0; s < 10; ++s) {
        int step = kg * 10 + s;               // global 32-wide k-step, 0..39
        int k = step * 32 + kq * 8;
        shortx8 xf = *(const shortx8*)(xrow + k);
#pragma unroll
        for (int ct = 0; ct < 4; ++ct) {
            shortx8 bfr = *(const shortx8*)(Abp + ((size_t)(step * 4 + ct) * 64 + lane) * 8);
            acc[ct] = __builtin_amdgcn_mfma_f32_16x16x32_bf16(xf, bfr, acc[ct], 0, 0, 0);
        }
    }
#pragma unroll
    for (int ct = 0; ct < 4; ++ct)
#pragma unroll
        for (int reg = 0; reg < 4; ++reg)
            hs[kg][wv * 16 + kq * 4 + reg][ct * 16 + mi] = acc[ct][reg];
    __syncthreads();

    int r = tid >> 4;                         // 0..63 local row
    int c0 = (tid & 15) * 4;                  // 0..60 rank col (4-aligned)
    float4 s0 = *(const float4*)&hs[0][r][c0];
    float4 s1 = *(const float4*)&hs[1][r][c0];
    float4 s2 = *(const float4*)&hs[2][r][c0];
    float4 s3 = *(const float4*)&hs[3][r][c0];
    int n = c0 >> 4;                          // adapter (c0..c0+3 share it)
    int m = m0 + r;
    float wgt = scalings[n] * masks[n * S_LEN + (m & (S_LEN - 1))];
    float v0 = (s0.x + s1.x + s2.x + s3.x) * wgt;
    float v1 = (s0.y + s1.y + s2.y + s3.y) * wgt;
    float v2 = (s0.z + s1.z + s2.z + s3.z) * wgt;
    float v3 = (s0.w + s1.w + s2.w + s3.w) * wgt;
    uint2 packed;
    packed.x = (unsigned)bf16_rne(v0) | ((unsigned)bf16_rne(v1) << 16);
    packed.y = (unsigned)bf16_rne(v2) | ((unsigned)bf16_rne(v3) << 16);
    *(uint2*)(g + (size_t)m * NR + c0) = packed;
}

// ---- Kernel 5: out = [xb | g] @ Wcat^T + bias  (M=32768, N=1280, K=1344)
// m201 8-phase template: BM=BN=256, BK=64, 2 K-tiles/iter, 8 phases/iter.
// 512 threads = 8 waves (2M x 4N); per-wave output 128x64; 16 MFMA per phase.
// LDS 128 KiB: As[2][256x64] + Bs[2][256x64] (buf = tile parity).
//
// RACE-FIX (R2 post-mortem): A-reads touch BOTH 128-row staging halves every
// A-phase (wm=0 reads rows 0-127, wm=1 reads rows 128-255), so A(buf) is only
// freed after the SECOND A-read phase (ph2 for buf0, ph6 for buf1). R2 staged
// A(N0)h0 at ph1 and A(N1)h0 at ph5 -> overwrote live data. Corrected slots
// (each at the earliest phase after its region's final read + end-barrier):
//   ph0: A(T1)h1      ph2: B(N0)h0      ph3: B(N0)h1 + A(N0)h0
//   ph4: A(N0)h1      ph6: B(N1)h0      ph7: B(N1)h1 + A(N1)h0
// vmcnt invariant: entering ph0, 6 outstanding = T1's {Bh0,Bh1,Ah0}; ph0 adds
// A(T1)h1 -> ph3's vmcnt(6) retires oldest 8 = tile T1. After ph3, 6 = N0's
// {Bh0,Bh1,Ah0}; ph4 adds A(N0)h1 -> ph7's vmcnt(6) retires N0's 8.
// Last iteration skips N1 stages, drains vmcnt(0); tail tile 20 (g cols) = 4
// stage-free phases. LDS swizzle (R1-verified 0 conflicts): 16B-slot ^ (row&7),
// pre-swizzled GLOBAL source (rule #21).
__global__ __launch_bounds__(512, 2) void k_main_gemm(const unsigned short* __restrict__ xb,
                                                      const unsigned short* __restrict__ g,
                                                      const unsigned short* __restrict__ Wcat,
                                                      const float* __restrict__ bias,
                                                      float* __restrict__ out) {
    __shared__ alignas(16) unsigned short As[2][256 * 64];
    __shared__ alignas(16) unsigned short Bs[2][256 * 64];

    const int tid = threadIdx.x;
    const int wave = tid >> 6, lane = tid & 63;
    const int wm = wave >> 2, wn = wave & 3;        // 2M x 4N wave grid
    const int mi = lane & 15, kq = lane >> 4;

    // XCD-bijective swizzle: 640 blocks = 8 XCDs x 80 slots = 16 row-tiles x 5 col-tiles,
    // col fastest -> same-row blocks co-resident, xb row-panel L2-hot.
    int bx = blockIdx.x;
    int xcd = bx & 7, slot = bx >> 3;               // slot 0..79
    int srb = slot / 5;
    const int m0 = (xcd * 16 + srb) * 256;
    const int n0 = (slot - srb * 5) * 256;

    // staging: chunk = 64 rows x 64 cols = 8 KB = 1 gload_lds per thread.
    const int tr = tid >> 3;                        // row within chunk
    const int ts = (tid & 7) ^ (tr & 7);            // pre-swizzled 16B column slot

    const unsigned short* pA = xb   + (size_t)(m0 + tr) * DIN + ts * 8;
    const unsigned short* pG = g    + (size_t)(m0 + tr) * NR  + ts * 8;
    const unsigned short* pB = Wcat + (size_t)(n0 + tr) * KC  + ts * 8;

    // read-side swizzled lane offsets (row&7 == mi&7 for all fragment rows)
    const int swz  = mi & 7;
    const int loK0 = mi * 128 + (((0) + kq) ^ swz) * 16;   // k-sub 0
    const int loK1 = mi * 128 + (((4) + kq) ^ swz) * 16;   // k-sub 1
    const int rbA  = (wm * 128) * 128;              // wave A row-block byte offset
    const int rbB  = (wn * 64) * 128;               // wave B row-block byte offset

    floatx4 acc[8][4] = {};
    shortx8 a[8];                                   // current A-half: 4 m-frags x 2 ksubs
    shortx8 b[2][4];                                // both B-halves: 2 n-frags x 2 ksubs each

    auto stA = [&](int t, int h) {                  // stage A half h of tile t -> buf t&1
        unsigned short* d = &As[t & 1][(h * 128) * 64 + tid * 8];
        if (t < 20) {
            const unsigned short* s = pA + (size_t)(h * 128) * DIN + t * 64;
            async16(s, d);
            async16(s + (size_t)64 * DIN, d + 64 * 64);
        } else {                                    // tile 20 = LoRA columns from g
            const unsigned short* s = pG + (size_t)(h * 128) * NR;
            async16(s, d);
            async16(s + (size_t)64 * NR, d + 64 * 64);
        }
    };
    auto stB = [&](int t, int h) {
        const unsigned short* s = pB + (size_t)(h * 128) * KC + t * 64;
        unsigned short* d = &Bs[t & 1][(h * 128) * 64 + tid * 8];
        async16(s, d);
        async16(s + (size_t)64 * KC, d + 64 * 64);
    };

#define READ_A(bufb, mh)  _Pragma("unroll") \
    for (int fm = 0; fm < 4; ++fm) { \
        const char* p = (const char*)As[bufb] + rbA + ((mh) * 64 + fm * 16) * 128; \
        a[fm * 2 + 0] = *(const shortx8*)(p + loK0); \
        a[fm * 2 + 1] = *(const shortx8*)(p + loK1); \
    }
#define READ_B(bufb, nh)  _Pragma("unroll") \
    for (int fn = 0; fn < 2; ++fn) { \
        const char* p = (const char*)Bs[bufb] + rbB + ((nh) * 32 + fn * 16) * 128; \
        b[nh][fn * 2 + 0] = *(const shortx8*)(p + loK0); \
        b[nh][fn * 2 + 1] = *(const shortx8*)(p + loK1); \
    }
#define MFMA16(mh, nh)  do { __builtin_amdgcn_s_setprio(1); \
    _Pragma("unroll") \
    for (int fm = 0; fm < 4; ++fm) \
        _Pragma("unroll") \
        for (int fn = 0; fn < 2; ++fn) { \
            acc[(mh)*4+fm][(nh)*2+fn] = __builtin_amdgcn_mfma_f32_16x16x32_bf16( \
                a[fm*2+0], b[nh][fn*2+0], acc[(mh)*4+fm][(nh)*2+fn], 0, 0, 0); \
            acc[(mh)*4+fm][(nh)*2+fn] = __builtin_amdgcn_mfma_f32_16x16x32_bf16( \
                a[fm*2+1], b[nh][fn*2+1], acc[(mh)*4+fm][(nh)*2+fn], 0, 0, 0); \
        } \
    __builtin_amdgcn_s_setprio(0); } while (0)

    // prologue: tile0 (8 loads) then tile1's {Bh0, Bh1, Ah0} (6 loads) — the order
    // that establishes the steady-state invariant. vmcnt(6) -> tile0 landed.
    stA(0, 0); stA(0, 1); stB(0, 0); stB(0, 1);
    stB(1, 0); stB(1, 1); stA(1, 0);
    VMCNT(6);
    barx();

    for (int it = 0; it < 10; ++it) {
        const int T1 = 2 * it + 1, N0 = 2 * it + 2, N1 = 2 * it + 3;
        const bool lastI = (it == 9);

        // ---- phase 0: tile T0 (buf0) quad(0,0); stage A(T1)h1 (buf1 A freed prior ph6)
        READ_A(0, 0); READ_B(0, 0);
        stA(T1, 1);
        barx(); LGKM0;
        MFMA16(0, 0);
        barx();
        // ---- phase 1: quad(0,1); NO stage (nothing freed yet)
        READ_B(0, 1);
        barx(); LGKM0;
        MFMA16(0, 1);
        barx();
        // ---- phase 2: quad(1,0); B(buf0) freed after ph1 -> stage B(N0)h0
        READ_A(0, 1);
        stB(N0, 0);
        barx(); LGKM0;
        MFMA16(1, 0);
        barx();
        // ---- phase 3: quad(1,1); A(buf0) freed after ph2 -> B(N0)h1 + A(N0)h0;
        //      vmcnt(6): tile T1 (oldest 8) fully landed
        stB(N0, 1); stA(N0, 0);
        barx(); LGKM0;
        MFMA16(1, 1);
        VMCNT(6);
        barx();
        // ---- phase 4: tile T1 (buf1) quad(0,0); stage A(N0)h1
        READ_A(1, 0); READ_B(1, 0);
        stA(N0, 1);
        barx(); LGKM0;
        MFMA16(0, 0);
        barx();
        // ---- phase 5: quad(0,1); NO stage (A(buf1) still live until ph6)
        READ_B(1, 1);
        barx(); LGKM0;
        MFMA16(0, 1);
        barx();
        // ---- phase 6: quad(1,0); B(buf1) freed after ph5 -> stage B(N1)h0
        READ_A(1, 1);
        if (!lastI) stB(N1, 0);
        barx(); LGKM0;
        MFMA16(1, 0);
        barx();
        // ---- phase 7: quad(1,1); A(buf1) freed after ph6 -> B(N1)h1 + A(N1)h0;
        //      vmcnt(6): tile N0 (oldest 8) fully landed
        if (!lastI) { stB(N1, 1); stA(N1, 0); }
        barx(); LGKM0;
        MFMA16(1, 1);
        if (lastI) { VMCNT(0); } else { VMCNT(6); }
        barx();
    }

    // ---- tail: tile 20 (buf0), 4 stage-free phases
    READ_A(0, 0); READ_B(0, 0);
    LGKM0;
    MFMA16(0, 0);
    READ_B(0, 1);
    LGKM0;
    MFMA16(0, 1);
    READ_A(0, 1);
    LGKM0;
    MFMA16(1, 0);
    MFMA16(1, 1);

    // ---- epilogue: C/D layout col = lane&15, row = (lane>>4)*4 + reg
    float bv[4];
#pragma unroll
    for (int nf = 0; nf < 4; ++nf)
        bv[nf] = bias[n0 + wn * 64 + (nf >> 1) * 32 + (nf & 1) * 16 + mi];
#pragma unroll
    for (int mf = 0; mf < 8; ++mf) {
        const int row = m0 + wm * 128 + (mf >> 2) * 64 + (mf & 3) * 16 + kq * 4;
#pragma unroll
        for (int nf = 0; nf < 4; ++nf) {
            const int col = n0 + wn * 64 + (nf >> 1) * 32 + (nf & 1) * 16 + mi;
            float* op = out + (size_t)row * DOUT + col;
#pragma unroll
            for (int reg = 0; reg < 4; ++reg)
                op[(size_t)reg * DOUT] = acc[mf][nf][reg] + bv[nf];
        }
    }
#undef READ_A
#undef READ_B
#undef MFMA16
}

extern "C" void kernel_launch(void* const* d_in, const int* in_sizes, int n_in,
                              void* d_out, int out_size, void* d_ws, size_t ws_size,
                              hipStream_t stream) {
    const float* x     = (const float*)d_in[0];  // (8,4096,1280)
    const float* W     = (const float*)d_in[1];  // (1280,1280)
    const float* bias  = (const float*)d_in[2];  // (1280,)
    const float* A     = (const float*)d_in[3];  // (4,16,1280)
    const float* Bw    = (const float*)d_in[4];  // (4,1280,16)
    const float* scal  = (const float*)d_in[5];  // (4,)
    const float* masks = (const float*)d_in[6];  // (4,4096)
    float* out = (float*)d_out;

    unsigned short* xb   = (unsigned short*)d_ws;            // 32768 x 1280 bf16
    unsigned short* g    = xb + (size_t)M_TOT * DIN;         // 32768 x 64 bf16
    unsigned short* Wcat = g + (size_t)M_TOT * NR;           // 1280 x 1344 bf16
    unsigned short* Abp  = Wcat + (size_t)DOUT * KC;         // 40*4*64*8 bf16

    k_convert_x<<<(M_TOT * DIN) / (8 * 256), 256, 0, stream>>>(x, xb);
    k_build_wcat<<<(DOUT * KC) / (8 * 256), 256, 0, stream>>>(W, Bw, Wcat);
    k_convert_abp<<<DIN / 32, 256, 0, stream>>>(A, Abp);
    k_lora_g<<<M_TOT / 64, 1024, 0, stream>>>(xb, Abp, scal, masks, g);
    k_main_gemm<<<(M_TOT / 256) * (DOUT / 256), 512, 0, stream>>>(xb, g, Wcat, bias, out);
}